// Round 4
// baseline (956.165 us; speedup 1.0000x reference)
//
#include <hip/hip_runtime.h>
#include <stdint.h>

#define NN 10000      // nodes
#define NE 160000     // edges (paired: e and e^1 are fwd/rev)
#define HID 300
#define NF 133
#define EF 14
#define NG 64

#define BR 64         // edge rows per GEMM block
#define NT 19         // n-tiles of 16 (304 padded cols)
#define WGRAN (NT*64) // 1216 16B-granules of W per k-step
#define CSTRIDE 312   // LDS C-tile column stride (ushorts)

typedef __bf16 bf16x8 __attribute__((ext_vector_type(8)));
typedef float f32x4 __attribute__((ext_vector_type(4)));

union GR { bf16x8 v; unsigned short s[8]; uint4 u; };

__device__ __forceinline__ float bf2f(unsigned short u) {
  union { unsigned int i; float f; } x; x.i = ((unsigned int)u) << 16; return x.f;
}
__device__ __forceinline__ unsigned short f2bf(float f) {
  union { float f; unsigned int i; } x; x.f = f;
  unsigned int r = x.i + 0x7fffu + ((x.i >> 16) & 1u);
  return (unsigned short)(r >> 16);
}

// ---------------- small utilities ----------------
__global__ void zero_kernel(int* __restrict__ p, int n) {
  int i = blockIdx.x * 256 + threadIdx.x;
  if (i < n) p[i] = 0;
}

// ---------------- CSR build over col ----------------
__global__ void hist_kernel(const int* __restrict__ col, int* __restrict__ cnt) {
  int e = blockIdx.x * 256 + threadIdx.x;
  if (e < NE) atomicAdd(&cnt[col[e]], 1);
}

__global__ void scan_kernel(const int* __restrict__ cnt, int* __restrict__ indptr) {
  __shared__ int part[1024];
  int t = threadIdx.x;
  int base = t * 10;
  int loc[10];
  int s = 0;
  #pragma unroll
  for (int i = 0; i < 10; ++i) {
    int n = base + i;
    int v = (n < NN) ? cnt[n] : 0;
    loc[i] = s; s += v;
  }
  part[t] = s;
  __syncthreads();
  for (int off = 1; off < 1024; off <<= 1) {
    int v = part[t];
    int u = (t >= off) ? part[t - off] : 0;
    __syncthreads();
    part[t] = v + u;
    __syncthreads();
  }
  int pre = (t == 0) ? 0 : part[t - 1];
  #pragma unroll
  for (int i = 0; i < 10; ++i) {
    int n = base + i;
    if (n <= NN) indptr[n] = pre + loc[i];
  }
}

// consumes cnt back to zero (self-restoring across graph replays)
__global__ void scatter_kernel(const int* __restrict__ col, const int* __restrict__ indptr,
                               int* __restrict__ cnt, int* __restrict__ eids) {
  int e = blockIdx.x * 256 + threadIdx.x;
  if (e < NE) {
    int v = col[e];
    int p = atomicSub(&cnt[v], 1) - 1;
    eids[indptr[v] + p] = e;
  }
}

// ---------------- segment_sum(h[bf16], col) -> a[f32] via CSR ----------------
__global__ void segsum_kernel(const unsigned short* __restrict__ h,
                              const int* __restrict__ indptr, const int* __restrict__ eids,
                              float* __restrict__ a) {
  int v = blockIdx.x;
  int t = threadIdx.x;
  int beg = indptr[v], end = indptr[v + 1];
  float s0a = 0.f, s1a = 0.f, s0b = 0.f, s1b = 0.f;
  float s0c = 0.f, s1c = 0.f, s0d = 0.f, s1d = 0.f;
  int p = beg;
  for (; p + 4 <= end; p += 4) {
    int e0 = eids[p], e1 = eids[p + 1], e2 = eids[p + 2], e3 = eids[p + 3];
    const unsigned short* h0r = h + (size_t)e0 * HID;
    const unsigned short* h1r = h + (size_t)e1 * HID;
    const unsigned short* h2r = h + (size_t)e2 * HID;
    const unsigned short* h3r = h + (size_t)e3 * HID;
    s0a += bf2f(h0r[t]); s0b += bf2f(h1r[t]);
    s0c += bf2f(h2r[t]); s0d += bf2f(h3r[t]);
    if (t < HID - 256) {
      s1a += bf2f(h0r[256 + t]); s1b += bf2f(h1r[256 + t]);
      s1c += bf2f(h2r[256 + t]); s1d += bf2f(h3r[256 + t]);
    }
  }
  for (; p < end; ++p) {
    int e = eids[p];
    const unsigned short* hr = h + (size_t)e * HID;
    s0a += bf2f(hr[t]);
    if (t < HID - 256) s1a += bf2f(hr[256 + t]);
  }
  a[(size_t)v * HID + t] = (s0a + s0b) + (s0c + s0d);
  if (t < HID - 256) a[(size_t)v * HID + 256 + t] = (s1a + s1b) + (s1c + s1d);
}

// ---------------- weight pre-transpose into MFMA fragment order -------------
// dst granule (kt,nt,lane l) holds W[kt*32 + (l>>4)*8 + i][nt*16 + (l&15)], i=0..7
__global__ void wtrans_kernel(const float* __restrict__ W, int K,
                              unsigned short* __restrict__ dst) {
  const int b = blockIdx.x;          // kt*NT + nt
  const int l = threadIdx.x;         // 0..63
  const int kt = b / NT, nt = b - kt * NT;
  const int k0 = kt * 32 + ((l >> 4) << 3);
  const int n  = (nt << 4) + (l & 15);
  GR g;
  #pragma unroll
  for (int i = 0; i < 8; ++i) {
    const int k = k0 + i;
    float f = (k < K && n < HID) ? W[(size_t)k * HID + n] : 0.f;
    g.s[i] = f2bf(f);
  }
  *(uint4*)(dst + ((size_t)(b * 64 + l) << 3)) = g.u;
}

// ---------------- MFMA GEMM, barrier-light, register-direct -----------------
// Per block: 64 rows x 304 cols. Waves split the 19 n-tiles (5/5/5/4).
// All MFMA operands loaded straight from global (L2-hot) — no LDS staging.
// MODE 0: edge_init  h0 = relu([x[row]|ea] @ W + b); also copy into h
// MODE 1: conv       h[e] = relu((a[row[e]] - bf(h[e^1])) @ W + b + bf(h0[e]))
//                    in-place on h: reads in k-loop, one barrier, then write-out
// MODE 2: node MLP   hn = relu([x|s] @ W + b)  (f32 out, direct epilogue)
// K-tail note: wbt is zero-padded for k >= K, so A-fragment garbage in the
// tail multiplies by 0; OOB-by-tail reads stay inside d_ws (see launch layout).
template<int MODE, int KTILES>
__global__ __launch_bounds__(256, 2)
void gemm_kernel(const float* __restrict__ xin,
                 const int* __restrict__ rowidx,
                 const float* __restrict__ aux,        // MODE0: edge_attr ; MODE2: s
                 const float* __restrict__ agg,        // MODE1: a
                 const unsigned short* hcur,           // MODE1 in (aliases outA)
                 const unsigned short* __restrict__ h0,
                 const unsigned short* __restrict__ wbt,  // fragment-ordered bf16 W^T
                 const float* __restrict__ bias,
                 unsigned short* outA,
                 unsigned short* outB,
                 float* __restrict__ outF)
{
  __shared__ unsigned short C_s[BR * CSTRIDE];   // 39936 B epilogue staging

  const int t = threadIdx.x;
  const int l = t & 63;
  const int wave = t >> 6;
  const int lr = l & 15;             // row within 16-tile
  const int lg = l >> 4;             // k-block / output col-group
  const int r0 = blockIdx.x * BR;
  const int nt0 = wave * 5;
  const int ntc = (wave == 3) ? 4 : 5;

  int re[4], ep[4], ei[4];
  #pragma unroll
  for (int et = 0; et < 4; ++et) {
    const int e = r0 + (et << 4) + lr;
    ei[et] = e;
    ep[et] = e ^ 1;
    re[et] = (MODE == 2) ? e : rowidx[e];
  }

  f32x4 acc[5][4];
  #pragma unroll
  for (int ni = 0; ni < 5; ++ni)
    #pragma unroll
    for (int et = 0; et < 4; ++et) acc[ni][et] = (f32x4)0.f;

  #pragma unroll 2
  for (int kt = 0; kt < KTILES; ++kt) {
    const int k0 = (kt << 5) + (lg << 3);
    GR ef[4];
    if (MODE == 1) {
      #pragma unroll
      for (int et = 0; et < 4; ++et) {
        const float* ap = agg + (size_t)re[et] * HID + k0;
        const unsigned short* hp = hcur + (size_t)ep[et] * HID + k0;
        const float4 a0 = *(const float4*)ap;
        const float4 a1 = *(const float4*)(ap + 4);
        const ushort4 hv0 = *(const ushort4*)hp;
        const ushort4 hv1 = *(const ushort4*)(hp + 4);
        ef[et].s[0] = f2bf(a0.x - bf2f(hv0.x)); ef[et].s[1] = f2bf(a0.y - bf2f(hv0.y));
        ef[et].s[2] = f2bf(a0.z - bf2f(hv0.z)); ef[et].s[3] = f2bf(a0.w - bf2f(hv0.w));
        ef[et].s[4] = f2bf(a1.x - bf2f(hv1.x)); ef[et].s[5] = f2bf(a1.y - bf2f(hv1.y));
        ef[et].s[6] = f2bf(a1.z - bf2f(hv1.z)); ef[et].s[7] = f2bf(a1.w - bf2f(hv1.w));
      }
    } else if (MODE == 0) {
      #pragma unroll
      for (int et = 0; et < 4; ++et) {
        const float* xr = xin + (size_t)re[et] * NF;
        const float* ar = aux + (size_t)ei[et] * EF - NF;
        #pragma unroll
        for (int i = 0; i < 8; ++i) {
          const int k = k0 + i;
          float f = 0.f;
          if (k < NF) f = xr[k];
          else if (k < NF + EF) f = ar[k];
          ef[et].s[i] = f2bf(f);
        }
      }
    } else {
      #pragma unroll
      for (int et = 0; et < 4; ++et) {
        const int node = ei[et];
        const float* xr = xin + (size_t)node * NF;
        const float* ar = aux + (size_t)node * HID - NF;
        #pragma unroll
        for (int i = 0; i < 8; ++i) {
          const int k = k0 + i;
          float f = 0.f;
          if (node < NN) {
            if (k < NF) f = xr[k];
            else if (k < NF + HID) f = ar[k];
          }
          ef[et].s[i] = f2bf(f);
        }
      }
    }
    const unsigned short* wk = wbt + (((size_t)kt * WGRAN + nt0 * 64 + l) << 3);
    #pragma unroll
    for (int ni = 0; ni < 5; ++ni) {
      if (ni < ntc) {
        const bf16x8 wf = *(const bf16x8*)(wk + ((size_t)ni << 9));
        #pragma unroll
        for (int et = 0; et < 4; ++et)
          acc[ni][et] = __builtin_amdgcn_mfma_f32_16x16x32_bf16(wf, ef[et].v, acc[ni][et], 0, 0, 0);
      }
    }
  }

  if (MODE == 2) {
    // direct scattered epilogue (small: 157 blocks, 12 MB out)
    #pragma unroll
    for (int ni = 0; ni < 5; ++ni) {
      if (ni >= ntc) continue;
      const int n = ((nt0 + ni) << 4) + (lg << 2);
      if (n >= HID) continue;
      const float4 bv = *(const float4*)(bias + n);
      #pragma unroll
      for (int et = 0; et < 4; ++et) {
        const int node = ei[et];
        if (node >= NN) continue;
        float v0 = fmaxf(acc[ni][et][0] + bv.x, 0.f);
        float v1 = fmaxf(acc[ni][et][1] + bv.y, 0.f);
        float v2 = fmaxf(acc[ni][et][2] + bv.z, 0.f);
        float v3 = fmaxf(acc[ni][et][3] + bv.w, 0.f);
        *(float4*)(outF + (size_t)node * HID + n) = make_float4(v0, v1, v2, v3);
      }
    }
    return;
  }

  // ---- stage C tile (acc + bias, pre-relu) into LDS ----
  #pragma unroll
  for (int ni = 0; ni < 5; ++ni) {
    if (ni >= ntc) continue;
    const int n = ((nt0 + ni) << 4) + (lg << 2);
    float4 bv = make_float4(0.f, 0.f, 0.f, 0.f);
    if (n < HID) bv = *(const float4*)(bias + n);
    #pragma unroll
    for (int et = 0; et < 4; ++et) {
      const int row = (et << 4) + lr;
      ushort4 o;
      o.x = f2bf(acc[ni][et][0] + bv.x);
      o.y = f2bf(acc[ni][et][1] + bv.y);
      o.z = f2bf(acc[ni][et][2] + bv.z);
      o.w = f2bf(acc[ni][et][3] + bv.w);
      *(ushort4*)(C_s + row * CSTRIDE + n) = o;
    }
  }
  __syncthreads();

  // ---- linear write-out: 64 rows x 75 ushort4-chunks, fully coalesced ----
  {
    const size_t base = (size_t)r0 * HID;
    for (int s = t; s < BR * 75; s += 256) {
      const int row = s / 75;
      const int idx = s - row * 75;
      const ushort4 c = *(const ushort4*)(C_s + row * CSTRIDE + (idx << 2));
      float v0 = bf2f(c.x), v1 = bf2f(c.y), v2 = bf2f(c.z), v3 = bf2f(c.w);
      const size_t off = base + (size_t)row * HID + (idx << 2);
      if (MODE == 1) {
        const ushort4 hz = *(const ushort4*)(h0 + off);
        v0 += bf2f(hz.x); v1 += bf2f(hz.y); v2 += bf2f(hz.z); v3 += bf2f(hz.w);
      }
      ushort4 o;
      o.x = f2bf(fmaxf(v0, 0.f)); o.y = f2bf(fmaxf(v1, 0.f));
      o.z = f2bf(fmaxf(v2, 0.f)); o.w = f2bf(fmaxf(v3, 0.f));
      *(ushort4*)(outA + off) = o;
      if (MODE == 0) *(ushort4*)(outB + off) = o;
    }
  }
}

// ---------------- output init + fused dot/pool ----------------
__global__ void init_out_kernel(float* __restrict__ out, const float* __restrict__ b_ffn) {
  int t = threadIdx.x;
  if (t < NG) out[t] = b_ffn[0];
}

__global__ void dotpool_kernel(const float* __restrict__ hn, const float* __restrict__ wffn,
                               const int* __restrict__ batch, float* __restrict__ out) {
  const int wave = threadIdx.x >> 6, lane = threadIdx.x & 63;
  const int v = blockIdx.x * 4 + wave;
  if (v >= NN) return;
  float s = 0.f;
  for (int j = lane; j < HID; j += 64) s += hn[(size_t)v * HID + j] * wffn[j];
  #pragma unroll
  for (int off = 32; off > 0; off >>= 1) s += __shfl_down(s, off, 64);
  if (lane == 0) atomicAdd(&out[batch[v]], s);
}

// ---------------- launch ----------------
extern "C" void kernel_launch(void* const* d_in, const int* in_sizes, int n_in,
                              void* d_out, int out_size, void* d_ws, size_t ws_size,
                              hipStream_t stream) {
  const float* x     = (const float*)d_in[0];
  const int*   eidx  = (const int*)d_in[1];
  const float* eattr = (const float*)d_in[2];
  const int*   batch = (const int*)d_in[3];
  const float* W_ei  = (const float*)d_in[4];
  const float* b_ei  = (const float*)d_in[5];
  const float* Ws    = (const float*)d_in[6];
  const float* bs    = (const float*)d_in[7];
  const float* W_en  = (const float*)d_in[8];
  const float* b_en  = (const float*)d_in[9];
  const float* W_ffn = (const float*)d_in[10];
  const float* b_ffn = (const float*)d_in[11];
  float* out = (float*)d_out;

  const int* row  = eidx;
  const int* colv = eidx + NE;

  // workspace layout (~218 MB). Ordering matters: h -> abuf -> hn gives the
  // K-tail overreads (<=40B past h, <=1.3KB past abuf) a safe landing zone.
  char* ws = (char*)d_ws;
  unsigned short* h0 = (unsigned short*)(ws + 0);              //  96,000,000 B
  unsigned short* h  = (unsigned short*)(ws + 96000000ull);    //  96,000,000 B
  float* abuf        = (float*)(ws + 192000000ull);            //  12,000,000 B
  float* hn          = (float*)(ws + 204000000ull);            //  12,000,000 B
  int* indptr        = (int*)(ws + 216000000ull);              //      40,004 B
  int* cnt           = (int*)(ws + 216040192ull);              //      40,000 B
  int* eids          = (int*)(ws + 216080384ull);              //     640,000 B
  unsigned short* wbt0 = (unsigned short*)(ws + 216720384ull); //      97,280 B (5 kt)
  unsigned short* wbtC = (unsigned short*)(ws + 216817664ull); //  3x 194,560 B (10 kt)
  unsigned short* wbtN = (unsigned short*)(ws + 217401344ull); //     272,384 B (14 kt)

  // CSR over col (scatter restores cnt to 0)
  zero_kernel<<<(NN + 255) / 256, 256, 0, stream>>>(cnt, NN);
  hist_kernel<<<NE / 256, 256, 0, stream>>>(colv, cnt);
  scan_kernel<<<1, 1024, 0, stream>>>(cnt, indptr);
  scatter_kernel<<<NE / 256, 256, 0, stream>>>(colv, indptr, cnt, eids);

  // weight pre-transposes (bf16, MFMA fragment order, zero-padded tails)
  wtrans_kernel<<<5 * NT, 64, 0, stream>>>(W_ei, NF + EF, wbt0);
  for (int lyr = 0; lyr < 3; ++lyr)
    wtrans_kernel<<<10 * NT, 64, 0, stream>>>(Ws + (size_t)lyr * HID * HID, HID,
                                              wbtC + (size_t)lyr * 10 * WGRAN * 8);
  wtrans_kernel<<<14 * NT, 64, 0, stream>>>(W_en, NF + HID, wbtN);

  // h0 = relu([x[row]|ea] @ W_ei + b_ei); h = h0
  gemm_kernel<0, 5><<<NE / BR, 256, 0, stream>>>(
      x, row, eattr, nullptr, nullptr, nullptr, wbt0, b_ei, h0, h, nullptr);

  for (int lyr = 0; lyr < 3; ++lyr) {
    segsum_kernel<<<NN, 256, 0, stream>>>(h, indptr, eids, abuf);
    gemm_kernel<1, 10><<<NE / BR, 256, 0, stream>>>(
        nullptr, row, nullptr, abuf, h, h0,
        wbtC + (size_t)lyr * 10 * WGRAN * 8, bs + (size_t)lyr * HID,
        h, nullptr, nullptr);                 // in-place update of h
  }

  // s = segsum(h, col); hn = relu([x|s] @ W_en + b_en)
  segsum_kernel<<<NN, 256, 0, stream>>>(h, indptr, eids, abuf);
  gemm_kernel<2, 14><<<(NN + BR - 1) / BR, 256, 0, stream>>>(
      x, nullptr, abuf, nullptr, nullptr, nullptr, wbtN, b_en,
      nullptr, nullptr, hn);

  // out[g] = b_ffn + sum_{batch[v]=g} hn[v] . W_ffn
  init_out_kernel<<<1, 64, 0, stream>>>(out, b_ffn);
  dotpool_kernel<<<NN / 4, 256, 0, stream>>>(hn, W_ffn, batch, out);
}

// Round 5
// 679.039 us; speedup vs baseline: 1.4081x; 1.4081x over previous
//
#include <hip/hip_runtime.h>
#include <stdint.h>

#define NN 10000      // nodes
#define NE 160000     // edges (paired: e and e^1 are fwd/rev)
#define HID 300
#define NF 133
#define EF 14
#define NG 64

#define BR 64         // edge rows per GEMM block
#define NT 19         // n-tiles of 16 (304 padded cols)
#define WGRAN (NT*64) // 1216 16B-granules of W per k-step
#define CSTRIDE 312   // LDS C-tile column stride (ushorts)

typedef __bf16 bf16x8 __attribute__((ext_vector_type(8)));
typedef float f32x4 __attribute__((ext_vector_type(4)));

union GR { bf16x8 v; unsigned short s[8]; uint4 u; };

__device__ __forceinline__ float bf2f(unsigned short u) {
  union { unsigned int i; float f; } x; x.i = ((unsigned int)u) << 16; return x.f;
}
__device__ __forceinline__ unsigned short f2bf(float f) {
  union { float f; unsigned int i; } x; x.f = f;
  unsigned int r = x.i + 0x7fffu + ((x.i >> 16) & 1u);
  return (unsigned short)(r >> 16);
}

// ---------------- small utilities ----------------
__global__ void zero_kernel(int* __restrict__ p, int n) {
  int i = blockIdx.x * 256 + threadIdx.x;
  if (i < n) p[i] = 0;
}

// ---------------- CSR build over col ----------------
__global__ void hist_kernel(const int* __restrict__ col, int* __restrict__ cnt) {
  int e = blockIdx.x * 256 + threadIdx.x;
  if (e < NE) atomicAdd(&cnt[col[e]], 1);
}

__global__ void scan_kernel(const int* __restrict__ cnt, int* __restrict__ indptr) {
  __shared__ int part[1024];
  int t = threadIdx.x;
  int base = t * 10;
  int loc[10];
  int s = 0;
  #pragma unroll
  for (int i = 0; i < 10; ++i) {
    int n = base + i;
    int v = (n < NN) ? cnt[n] : 0;
    loc[i] = s; s += v;
  }
  part[t] = s;
  __syncthreads();
  for (int off = 1; off < 1024; off <<= 1) {
    int v = part[t];
    int u = (t >= off) ? part[t - off] : 0;
    __syncthreads();
    part[t] = v + u;
    __syncthreads();
  }
  int pre = (t == 0) ? 0 : part[t - 1];
  #pragma unroll
  for (int i = 0; i < 10; ++i) {
    int n = base + i;
    if (n <= NN) indptr[n] = pre + loc[i];
  }
}

// consumes cnt back to zero (self-restoring across graph replays)
__global__ void scatter_kernel(const int* __restrict__ col, const int* __restrict__ indptr,
                               int* __restrict__ cnt, int* __restrict__ eids) {
  int e = blockIdx.x * 256 + threadIdx.x;
  if (e < NE) {
    int v = col[e];
    int p = atomicSub(&cnt[v], 1) - 1;
    eids[indptr[v] + p] = e;
  }
}

// ---------------- segment_sum(h[bf16], col) -> a[f32] via CSR ----------------
__global__ void segsum_kernel(const unsigned short* __restrict__ h,
                              const int* __restrict__ indptr, const int* __restrict__ eids,
                              float* __restrict__ a) {
  int v = blockIdx.x;
  int t = threadIdx.x;
  int beg = indptr[v], end = indptr[v + 1];
  float s0a = 0.f, s1a = 0.f, s0b = 0.f, s1b = 0.f;
  float s0c = 0.f, s1c = 0.f, s0d = 0.f, s1d = 0.f;
  int p = beg;
  for (; p + 4 <= end; p += 4) {
    int e0 = eids[p], e1 = eids[p + 1], e2 = eids[p + 2], e3 = eids[p + 3];
    const unsigned short* h0r = h + (size_t)e0 * HID;
    const unsigned short* h1r = h + (size_t)e1 * HID;
    const unsigned short* h2r = h + (size_t)e2 * HID;
    const unsigned short* h3r = h + (size_t)e3 * HID;
    s0a += bf2f(h0r[t]); s0b += bf2f(h1r[t]);
    s0c += bf2f(h2r[t]); s0d += bf2f(h3r[t]);
    if (t < HID - 256) {
      s1a += bf2f(h0r[256 + t]); s1b += bf2f(h1r[256 + t]);
      s1c += bf2f(h2r[256 + t]); s1d += bf2f(h3r[256 + t]);
    }
  }
  for (; p < end; ++p) {
    int e = eids[p];
    const unsigned short* hr = h + (size_t)e * HID;
    s0a += bf2f(hr[t]);
    if (t < HID - 256) s1a += bf2f(hr[256 + t]);
  }
  a[(size_t)v * HID + t] = (s0a + s0b) + (s0c + s0d);
  if (t < HID - 256) a[(size_t)v * HID + 256 + t] = (s1a + s1b) + (s1c + s1d);
}

// ---------------- weight pre-transpose into MFMA fragment order -------------
// dst granule (kt,nt,lane l) holds W[kt*32 + (l>>4)*8 + i][nt*16 + (l&15)], i=0..7
__global__ void wtrans_kernel(const float* __restrict__ W, int K,
                              unsigned short* __restrict__ dst) {
  const int b = blockIdx.x;          // kt*NT + nt
  const int l = threadIdx.x;         // 0..63
  const int kt = b / NT, nt = b - kt * NT;
  const int k0 = kt * 32 + ((l >> 4) << 3);
  const int n  = (nt << 4) + (l & 15);
  GR g;
  #pragma unroll
  for (int i = 0; i < 8; ++i) {
    const int k = k0 + i;
    float f = (k < K && n < HID) ? W[(size_t)k * HID + n] : 0.f;
    g.s[i] = f2bf(f);
  }
  *(uint4*)(dst + ((size_t)(b * 64 + l) << 3)) = g.u;
}

// ---------------- MFMA GEMM: stage-once A in fragment order -----------------
// Per block: 64 rows x 304 cols. Waves split the 19 n-tiles (5/5/5/4).
// A-operand staged ONCE into LDS in MFMA fragment order [kg][row]x16B, so the
// k-loop is barrier-free: 4 lane-linear ds_read_b128 + 5 L2-hot W loads + 20
// MFMA per k-step. W fragments read direct from L2 (same addrs for all blocks).
// MODE 0: edge_init  h0 = relu([x[row]|ea] @ W + b); also copy into h
// MODE 1: conv       h[e] = relu((a[row[e]] - bf(h[e^1])) @ W + b + bf(h0[e]))
//                    in-place on h: all h reads in prologue, writes at the end
// MODE 2: node MLP   hn = relu([x|s] @ W + b)  (f32 out, direct epilogue)
template<int MODE, int KTILES>
__global__ __launch_bounds__(256, 3)
void gemm_kernel(const float* __restrict__ xin,
                 const int* __restrict__ rowidx,
                 const float* __restrict__ aux,        // MODE0: edge_attr ; MODE2: s
                 const float* __restrict__ agg,        // MODE1: a
                 const unsigned short* hcur,           // MODE1 in (aliases outA)
                 const unsigned short* __restrict__ h0,
                 const unsigned short* __restrict__ wbt,  // fragment-ordered bf16 W^T
                 const float* __restrict__ bias,
                 unsigned short* outA,
                 unsigned short* outB,
                 float* __restrict__ outF)
{
  constexpr int NKG = KTILES * 4;                 // 16B k-granules per row
  constexpr int STAGE_USH = NKG * 64 * 8;         // staged A, fragment order
  constexpr int LDS_USH = (STAGE_USH > BR * CSTRIDE) ? STAGE_USH : BR * CSTRIDE;
  __shared__ unsigned short S_lds[LDS_USH];       // A-stage, then C-tile
  __shared__ int rowv[BR];

  const int t = threadIdx.x;
  const int l = t & 63;
  const int wave = t >> 6;
  const int lr = l & 15;             // row within 16-tile
  const int lg = l >> 4;             // k-granule within k-step / output col-group
  const int r0 = blockIdx.x * BR;
  const int nt0 = wave * 5;
  const int ntc = (wave == 3) ? 4 : 5;

  if (MODE != 2 && t < BR) rowv[t] = rowidx[r0 + t];
  __syncthreads();

  // ---- stage A once: granule s (8B, 4 elems) -> S_lds[s*8B] (lane-linear) --
  // element (kg, row, j) lives at ushort (kg*64 + row)*8 + j  == k = kg*8+j
  #pragma unroll
  for (int it = 0; it < NKG / 2; ++it) {
    const int s = t + (it << 8);                  // 0 .. NKG*128-1
    const int half = s & 1;
    const int idx16 = s >> 1;
    const int kg = idx16 >> 6;
    const int row = idx16 & 63;
    const int k = (kg << 3) + (half << 2);
    ushort4 o = make_ushort4(0, 0, 0, 0);
    if (MODE == 1) {
      if (k < HID) {
        const int r = rowv[row];
        const int ep = (r0 + row) ^ 1;
        const float4 av = *(const float4*)(agg + (size_t)r * HID + k);
        const ushort4 hv = *(const ushort4*)(hcur + (size_t)ep * HID + k);
        o.x = f2bf(av.x - bf2f(hv.x)); o.y = f2bf(av.y - bf2f(hv.y));
        o.z = f2bf(av.z - bf2f(hv.z)); o.w = f2bf(av.w - bf2f(hv.w));
      }
    } else if (MODE == 0) {
      const int r = rowv[row];
      unsigned short vv[4];
      #pragma unroll
      for (int q = 0; q < 4; ++q) {
        const int kk = k + q; float f = 0.f;
        if (kk < NF) f = xin[(size_t)r * NF + kk];
        else if (kk < NF + EF) f = aux[(size_t)(r0 + row) * EF + (kk - NF)];
        vv[q] = f2bf(f);
      }
      o.x = vv[0]; o.y = vv[1]; o.z = vv[2]; o.w = vv[3];
    } else {
      const int node = r0 + row;
      if (node < NN) {
        unsigned short vv[4];
        #pragma unroll
        for (int q = 0; q < 4; ++q) {
          const int kk = k + q; float f = 0.f;
          if (kk < NF) f = xin[(size_t)node * NF + kk];
          else if (kk < NF + HID) f = aux[(size_t)node * HID + (kk - NF)];
          vv[q] = f2bf(f);
        }
        o.x = vv[0]; o.y = vv[1]; o.z = vv[2]; o.w = vv[3];
      }
    }
    *(ushort4*)(S_lds + (size_t)s * 4) = o;
  }
  __syncthreads();

  f32x4 acc[5][4];
  #pragma unroll
  for (int ni = 0; ni < 5; ++ni)
    #pragma unroll
    for (int et = 0; et < 4; ++et) acc[ni][et] = (f32x4)0.f;

  // ---- barrier-free k-loop ----
  #pragma unroll 2
  for (int kt = 0; kt < KTILES; ++kt) {
    bf16x8 ef[4];
    #pragma unroll
    for (int et = 0; et < 4; ++et)
      ef[et] = *(const bf16x8*)(S_lds + (size_t)(((kt * 4 + lg) * 64 + et * 16 + lr)) * 8);
    const unsigned short* wk = wbt + (((size_t)kt * WGRAN + nt0 * 64 + l) << 3);
    #pragma unroll
    for (int ni = 0; ni < 5; ++ni) {
      if (ni < ntc) {
        const bf16x8 wf = *(const bf16x8*)(wk + ((size_t)ni << 9));
        #pragma unroll
        for (int et = 0; et < 4; ++et)
          acc[ni][et] = __builtin_amdgcn_mfma_f32_16x16x32_bf16(wf, ef[et], acc[ni][et], 0, 0, 0);
      }
    }
  }

  if (MODE == 2) {
    // direct scattered epilogue (small: 157 blocks, 12 MB out)
    #pragma unroll
    for (int ni = 0; ni < 5; ++ni) {
      if (ni >= ntc) continue;
      const int n = ((nt0 + ni) << 4) + (lg << 2);
      if (n >= HID) continue;
      const float4 bv = *(const float4*)(bias + n);
      #pragma unroll
      for (int et = 0; et < 4; ++et) {
        const int node = r0 + (et << 4) + lr;
        if (node >= NN) continue;
        float v0 = fmaxf(acc[ni][et][0] + bv.x, 0.f);
        float v1 = fmaxf(acc[ni][et][1] + bv.y, 0.f);
        float v2 = fmaxf(acc[ni][et][2] + bv.z, 0.f);
        float v3 = fmaxf(acc[ni][et][3] + bv.w, 0.f);
        *(float4*)(outF + (size_t)node * HID + n) = make_float4(v0, v1, v2, v3);
      }
    }
    return;
  }

  // ---- stage C tile (acc + bias, pre-relu) into LDS (reuses S_lds) ----
  __syncthreads();   // all fragment reads done before overwrite
  #pragma unroll
  for (int ni = 0; ni < 5; ++ni) {
    if (ni >= ntc) continue;
    const int n = ((nt0 + ni) << 4) + (lg << 2);
    float4 bv = make_float4(0.f, 0.f, 0.f, 0.f);
    if (n < HID) bv = *(const float4*)(bias + n);
    #pragma unroll
    for (int et = 0; et < 4; ++et) {
      const int row = (et << 4) + lr;
      ushort4 o;
      o.x = f2bf(acc[ni][et][0] + bv.x);
      o.y = f2bf(acc[ni][et][1] + bv.y);
      o.z = f2bf(acc[ni][et][2] + bv.z);
      o.w = f2bf(acc[ni][et][3] + bv.w);
      if (n < CSTRIDE) *(ushort4*)(S_lds + row * CSTRIDE + n) = o;
    }
  }
  __syncthreads();

  // ---- linear write-out: 64 rows x 75 ushort4-chunks, fully coalesced ----
  {
    const size_t base = (size_t)r0 * HID;
    for (int s = t; s < BR * 75; s += 256) {
      const int row = s / 75;
      const int idx = s - row * 75;
      const ushort4 c = *(const ushort4*)(S_lds + row * CSTRIDE + (idx << 2));
      float v0 = bf2f(c.x), v1 = bf2f(c.y), v2 = bf2f(c.z), v3 = bf2f(c.w);
      const size_t off = base + (size_t)row * HID + (idx << 2);
      if (MODE == 1) {
        const ushort4 hz = *(const ushort4*)(h0 + off);
        v0 += bf2f(hz.x); v1 += bf2f(hz.y); v2 += bf2f(hz.z); v3 += bf2f(hz.w);
      }
      ushort4 o;
      o.x = f2bf(fmaxf(v0, 0.f)); o.y = f2bf(fmaxf(v1, 0.f));
      o.z = f2bf(fmaxf(v2, 0.f)); o.w = f2bf(fmaxf(v3, 0.f));
      *(ushort4*)(outA + off) = o;
      if (MODE == 0) *(ushort4*)(outB + off) = o;
    }
  }
}

// ---------------- output init + fused dot/pool ----------------
__global__ void init_out_kernel(float* __restrict__ out, const float* __restrict__ b_ffn) {
  int t = threadIdx.x;
  if (t < NG) out[t] = b_ffn[0];
}

__global__ void dotpool_kernel(const float* __restrict__ hn, const float* __restrict__ wffn,
                               const int* __restrict__ batch, float* __restrict__ out) {
  const int wave = threadIdx.x >> 6, lane = threadIdx.x & 63;
  const int v = blockIdx.x * 4 + wave;
  if (v >= NN) return;
  float s = 0.f;
  for (int j = lane; j < HID; j += 64) s += hn[(size_t)v * HID + j] * wffn[j];
  #pragma unroll
  for (int off = 32; off > 0; off >>= 1) s += __shfl_down(s, off, 64);
  if (lane == 0) atomicAdd(&out[batch[v]], s);
}

// ---------------- launch ----------------
extern "C" void kernel_launch(void* const* d_in, const int* in_sizes, int n_in,
                              void* d_out, int out_size, void* d_ws, size_t ws_size,
                              hipStream_t stream) {
  const float* x     = (const float*)d_in[0];
  const int*   eidx  = (const int*)d_in[1];
  const float* eattr = (const float*)d_in[2];
  const int*   batch = (const int*)d_in[3];
  const float* W_ei  = (const float*)d_in[4];
  const float* b_ei  = (const float*)d_in[5];
  const float* Ws    = (const float*)d_in[6];
  const float* bs    = (const float*)d_in[7];
  const float* W_en  = (const float*)d_in[8];
  const float* b_en  = (const float*)d_in[9];
  const float* W_ffn = (const float*)d_in[10];
  const float* b_ffn = (const float*)d_in[11];
  float* out = (float*)d_out;

  const int* row  = eidx;
  const int* colv = eidx + NE;

  // workspace layout (~218 MB)
  char* ws = (char*)d_ws;
  unsigned short* h0 = (unsigned short*)(ws + 0);              //  96,000,000 B
  unsigned short* h  = (unsigned short*)(ws + 96000000ull);    //  96,000,000 B
  float* abuf        = (float*)(ws + 192000000ull);            //  12,000,000 B
  float* hn          = (float*)(ws + 204000000ull);            //  12,000,000 B
  int* indptr        = (int*)(ws + 216000000ull);              //      40,004 B
  int* cnt           = (int*)(ws + 216040192ull);              //      40,000 B
  int* eids          = (int*)(ws + 216080384ull);              //     640,000 B
  unsigned short* wbt0 = (unsigned short*)(ws + 216720384ull); //      97,280 B (5 kt)
  unsigned short* wbtC = (unsigned short*)(ws + 216817664ull); //  3x 194,560 B (10 kt)
  unsigned short* wbtN = (unsigned short*)(ws + 217401344ull); //     272,384 B (14 kt)

  // CSR over col (scatter restores cnt to 0)
  zero_kernel<<<(NN + 255) / 256, 256, 0, stream>>>(cnt, NN);
  hist_kernel<<<NE / 256, 256, 0, stream>>>(colv, cnt);
  scan_kernel<<<1, 1024, 0, stream>>>(cnt, indptr);
  scatter_kernel<<<NE / 256, 256, 0, stream>>>(colv, indptr, cnt, eids);

  // weight pre-transposes (bf16, MFMA fragment order, zero-padded tails)
  wtrans_kernel<<<5 * NT, 64, 0, stream>>>(W_ei, NF + EF, wbt0);
  for (int lyr = 0; lyr < 3; ++lyr)
    wtrans_kernel<<<10 * NT, 64, 0, stream>>>(Ws + (size_t)lyr * HID * HID, HID,
                                              wbtC + (size_t)lyr * 10 * WGRAN * 8);
  wtrans_kernel<<<14 * NT, 64, 0, stream>>>(W_en, NF + HID, wbtN);

  // h0 = relu([x[row]|ea] @ W_ei + b_ei); h = h0
  gemm_kernel<0, 5><<<NE / BR, 256, 0, stream>>>(
      x, row, eattr, nullptr, nullptr, nullptr, wbt0, b_ei, h0, h, nullptr);

  for (int lyr = 0; lyr < 3; ++lyr) {
    segsum_kernel<<<NN, 256, 0, stream>>>(h, indptr, eids, abuf);
    gemm_kernel<1, 10><<<NE / BR, 256, 0, stream>>>(
        nullptr, row, nullptr, abuf, h, h0,
        wbtC + (size_t)lyr * 10 * WGRAN * 8, bs + (size_t)lyr * HID,
        h, nullptr, nullptr);                 // in-place update of h
  }

  // s = segsum(h, col); hn = relu([x|s] @ W_en + b_en)
  segsum_kernel<<<NN, 256, 0, stream>>>(h, indptr, eids, abuf);
  gemm_kernel<2, 14><<<(NN + BR - 1) / BR, 256, 0, stream>>>(
      x, nullptr, abuf, nullptr, nullptr, nullptr, wbtN, b_en,
      nullptr, nullptr, hn);

  // out[g] = b_ffn + sum_{batch[v]=g} hn[v] . W_ffn
  init_out_kernel<<<1, 64, 0, stream>>>(out, b_ffn);
  dotpool_kernel<<<NN / 4, 256, 0, stream>>>(hn, W_ffn, batch, out);
}